// Round 1
// baseline (27.540 us; speedup 1.0000x reference)
//
#include <hip/hip_runtime.h>

#define BB 16
#define NN 65536
#define KK 64
#define TPB 256
#define EPT 4                       // elements per thread
#define ELEMS_PER_BLOCK (TPB * EPT) // 1024

__global__ __launch_bounds__(TPB) void frac_deriv_kernel(
    const float* __restrict__ x,
    const float* __restrict__ loc,
    const float* __restrict__ scale,
    const float* __restrict__ eps,
    const int* __restrict__ lags,
    float* __restrict__ out)
{
    __shared__ double w_sh[KK];
    __shared__ int    j_sh[KK];

    const int tid = threadIdx.x;
    if (tid < KK) {
        // alpha = clip(loc + softplus(scale)*eps, 0.01, 0.99), in double
        double s = (double)scale[0];
        double sp = (s > 20.0) ? s : log1p(exp(s));
        double a = (double)loc[0] + sp * (double)eps[0];
        a = fmin(fmax(a, 0.01), 0.99);
        // c = alpha * exp(-lgamma(1-alpha)) * (n-1)/k
        double c = a * exp(-lgamma(1.0 - a)) * ((double)(NN - 1) / (double)KK);
        int j = lags[tid];
        j = (j < 1) ? 1 : ((j > NN - 1) ? NN - 1 : j);
        j_sh[tid] = j;
        // fold c into the weight: w' = c * j^{-(a+1)}
        w_sh[tid] = c * exp(-(a + 1.0) * log((double)j));
    }
    __syncthreads();

    // Bijective XCD-aware swizzle (gridDim.x = 1024, divisible by 8):
    // each XCD gets 128 contiguous blocks = 2 full rows -> L2-resident.
    const int nwg = gridDim.x;
    const int cpx = nwg >> 3;
    const int bid = blockIdx.x;
    const int swz = (bid & 7) * cpx + (bid >> 3);

    const int segs_per_row = NN / ELEMS_PER_BLOCK; // 64
    const int b   = swz / segs_per_row;
    const int seg = swz % segs_per_row;

    const float* xr = x + (size_t)b * NN;
    const int t0 = seg * ELEMS_PER_BLOCK + tid;

    float xt[EPT];
#pragma unroll
    for (int i = 0; i < EPT; ++i) xt[i] = xr[t0 + i * TPB];

    double acc[EPT];
#pragma unroll
    for (int i = 0; i < EPT; ++i) acc[i] = 0.0;

#pragma unroll 2
    for (int m = 0; m < KK; ++m) {
        const int    j = j_sh[m];
        const double w = w_sh[m];
#pragma unroll
        for (int i = 0; i < EPT; ++i) {
            const int t = t0 + i * TPB;
            const int d = t - j;
            const float xg = xr[(d < 0) ? 0 : d];   // clamped gather (coalesced stream)
            const double contrib = (double)(xt[i] - xg) * w;
            acc[i] += (d >= 0) ? contrib : 0.0;     // mask: history must exist
        }
    }

    float* orow = out + (size_t)b * NN;
#pragma unroll
    for (int i = 0; i < EPT; ++i) orow[t0 + i * TPB] = (float)acc[i];
}

extern "C" void kernel_launch(void* const* d_in, const int* in_sizes, int n_in,
                              void* d_out, int out_size, void* d_ws, size_t ws_size,
                              hipStream_t stream) {
    const float* x     = (const float*)d_in[0];
    const float* loc   = (const float*)d_in[1];
    const float* scale = (const float*)d_in[2];
    const float* eps   = (const float*)d_in[3];
    const int*   lags  = (const int*)d_in[4];
    float* out = (float*)d_out;

    const int nblocks = (BB * NN) / ELEMS_PER_BLOCK; // 1024
    frac_deriv_kernel<<<nblocks, TPB, 0, stream>>>(x, loc, scale, eps, lags, out);
}